// Round 1
// 1118.205 us; speedup vs baseline: 2.0238x; 2.0238x over previous
//
#include <hip/hip_runtime.h>
#include <hip/hip_bf16.h>
#include <math.h>

#define DM 1024
#define NH 16
#define HD 64
#define BB 2
#define TT 2048
#define MROWS (BB*TT)   // 4096
#define TQ 64
#define TK 64

typedef __hip_bfloat16 bf16;
typedef unsigned short ushort_t;

using bf8_t = __attribute__((ext_vector_type(8))) __bf16;   // one MFMA A/B fragment (4 VGPRs)
using bf4_t = __attribute__((ext_vector_type(4))) __bf16;   // 8-byte LDS write chunk
using f4_t  = __attribute__((ext_vector_type(4))) float;    // MFMA C/D fragment

// ---------------------------------------------------------------------------
// Runtime input-dtype probe (flag=1 -> fp32 inputs, 0 -> bf16). Graph-safe.
// ---------------------------------------------------------------------------
__global__ void detect_dtype(const unsigned short* __restrict__ x, int* flag) {
    __shared__ int cnt;
    if (threadIdx.x == 0) cnt = 0;
    __syncthreads();
    int local = 0;
    for (int i = threadIdx.x; i < 512; i += 256) {
        unsigned short u = x[i];
        int e = (u >> 7) & 0xFF;
        if (e >= 117 && e <= 130) local++;
    }
    atomicAdd(&cnt, local);
    __syncthreads();
    if (threadIdx.x == 0) *flag = (cnt >= 384) ? 0 : 1;
}

// ---------------------------------------------------------------------------
// MFMA GEMM  Y[M,N] = A[M,K] * W[N,K]^T   (M=4096, N=K=1024)
// 128x128 tile, BK=64, 4 waves (each 64x64 out = 4x4 frags of 16x16x32 bf16).
// Error-free bf16 splitting:
//   MODE 0 (input proj): A dtype=flag, Y=f32.  flag=0 -> 1 term (exact),
//                        flag=1 -> 3-term hi/lo split (~2^-15 rel).
//   MODE 1 (out proj):   A=f32 ws, Y dtype=flag. A always hi/lo split.
// LDS: 4 x [128 rows][64 bf16] = 64 KiB, XOR-swizzled (byte ^= (row&7)<<4)
// so ds_read_b128 of a 16-lane column-slice spreads across all 32 banks.
// ---------------------------------------------------------------------------
__device__ __forceinline__ int swz(int r, int b) {
    return r * 128 + (b ^ ((r & 7) << 4));
}

template<int MODE>
__global__ __launch_bounds__(256) void gemm_mfma(const void* __restrict__ A,
                                                 const void* __restrict__ W,
                                                 void* __restrict__ Y,
                                                 const int* __restrict__ flag)
{
    const int f32 = *flag;
    __shared__ __align__(16) char sm[65536];
    char* const Ah = sm;
    char* const Wh = sm + 16384;
    char* const Al = sm + 32768;
    char* const Wl = sm + 49152;

    const int tid  = threadIdx.x;
    const int m0   = blockIdx.y * 128, n0 = blockIdx.x * 128;
    const int lane = tid & 63;
    const int wr   = ((tid >> 7) & 1) * 64;   // wave row offset in tile
    const int wc   = ((tid >> 6) & 1) * 64;   // wave col offset in tile
    const int lrow = lane & 15;               // fragment row/col within 16
    const int lkb  = (lane >> 4) * 16;        // byte offset of lane's k-group

    const bool aSplit = (MODE == 1) || (f32 != 0);
    const bool wSplit = (f32 != 0);

    f4_t acc[4][4] = {};

    for (int k0 = 0; k0 < DM; k0 += 64) {
        if (k0) __syncthreads();

        // ---- stage A tile (128 x 64) ----
        if (!aSplit) {                       // bf16 source, direct copy
            const ushort_t* Ab = (const ushort_t*)A;
            for (int u = tid; u < 1024; u += 256) {
                const int r = u >> 3, c = u & 7;
                bf8_t v = *(const bf8_t*)(Ab + (size_t)(m0 + r) * DM + k0 + c * 8);
                *(bf8_t*)(Ah + swz(r, c * 16)) = v;
            }
        } else {                             // fp32 source, hi/lo split
            const float* Af = (const float*)A;
            for (int u = tid; u < 2048; u += 256) {
                const int r = u >> 4, c = u & 15;
                float4 v = *(const float4*)(Af + (size_t)(m0 + r) * DM + k0 + c * 4);
                __bf16 h0 = (__bf16)v.x, h1 = (__bf16)v.y,
                       h2 = (__bf16)v.z, h3 = (__bf16)v.w;
                bf4_t hv = {h0, h1, h2, h3};
                bf4_t lv = {(__bf16)(v.x - (float)h0), (__bf16)(v.y - (float)h1),
                            (__bf16)(v.z - (float)h2), (__bf16)(v.w - (float)h3)};
                *(bf4_t*)(Ah + swz(r, c * 8)) = hv;
                *(bf4_t*)(Al + swz(r, c * 8)) = lv;
            }
        }
        // ---- stage W tile (128 x 64) ----
        if (!wSplit) {
            const ushort_t* Wb = (const ushort_t*)W;
            for (int u = tid; u < 1024; u += 256) {
                const int r = u >> 3, c = u & 7;
                bf8_t v = *(const bf8_t*)(Wb + (size_t)(n0 + r) * DM + k0 + c * 8);
                *(bf8_t*)(Wh + swz(r, c * 16)) = v;
            }
        } else {
            const float* Wf = (const float*)W;
            for (int u = tid; u < 2048; u += 256) {
                const int r = u >> 4, c = u & 15;
                float4 v = *(const float4*)(Wf + (size_t)(n0 + r) * DM + k0 + c * 4);
                __bf16 h0 = (__bf16)v.x, h1 = (__bf16)v.y,
                       h2 = (__bf16)v.z, h3 = (__bf16)v.w;
                bf4_t hv = {h0, h1, h2, h3};
                bf4_t lv = {(__bf16)(v.x - (float)h0), (__bf16)(v.y - (float)h1),
                            (__bf16)(v.z - (float)h2), (__bf16)(v.w - (float)h3)};
                *(bf4_t*)(Wh + swz(r, c * 8)) = hv;
                *(bf4_t*)(Wl + swz(r, c * 8)) = lv;
            }
        }
        __syncthreads();

        // ---- compute: 2 k-slices of 32 ----
#pragma unroll
        for (int kh = 0; kh < 2; kh++) {
            const int bc = kh * 64 + lkb;
            bf8_t ah[4], wh[4], al[4], wl[4];
#pragma unroll
            for (int i = 0; i < 4; i++) {
                ah[i] = *(const bf8_t*)(Ah + swz(wr + i * 16 + lrow, bc));
                wh[i] = *(const bf8_t*)(Wh + swz(wc + i * 16 + lrow, bc));
            }
            if (aSplit) {
#pragma unroll
                for (int i = 0; i < 4; i++)
                    al[i] = *(const bf8_t*)(Al + swz(wr + i * 16 + lrow, bc));
            }
            if (wSplit) {
#pragma unroll
                for (int i = 0; i < 4; i++)
                    wl[i] = *(const bf8_t*)(Wl + swz(wc + i * 16 + lrow, bc));
            }
#pragma unroll
            for (int m = 0; m < 4; m++)
#pragma unroll
                for (int n = 0; n < 4; n++) {
                    acc[m][n] = __builtin_amdgcn_mfma_f32_16x16x32_bf16(
                                    ah[m], wh[n], acc[m][n], 0, 0, 0);
                    if (aSplit)
                        acc[m][n] = __builtin_amdgcn_mfma_f32_16x16x32_bf16(
                                        al[m], wh[n], acc[m][n], 0, 0, 0);
                    if (wSplit)
                        acc[m][n] = __builtin_amdgcn_mfma_f32_16x16x32_bf16(
                                        ah[m], wl[n], acc[m][n], 0, 0, 0);
                }
        }
    }

    // ---- epilogue: C/D layout col=lane&15, row=(lane>>4)*4+reg ----
    const int orow = (lane >> 4) * 4;
    const int ocol = lane & 15;
#pragma unroll
    for (int m = 0; m < 4; m++)
#pragma unroll
        for (int n = 0; n < 4; n++) {
            const int gr = m0 + wr + m * 16 + orow;
            const int gc = n0 + wc + n * 16 + ocol;
#pragma unroll
            for (int r = 0; r < 4; r++) {
                const float v = acc[m][n][r];
                const size_t off = (size_t)(gr + r) * DM + gc;
                if (MODE == 0)      ((float*)Y)[off] = v;
                else if (f32)       ((float*)Y)[off] = v;
                else                ((__bf16*)Y)[off] = (__bf16)v;
            }
        }
}

// ---------------------------------------------------------------------------
// RoPE in-place on Q and K, layout [B*T, DM].  (unchanged)
// ---------------------------------------------------------------------------
__global__ void rope_kernel(float* __restrict__ Q, float* __restrict__ K) {
    const size_t idx = (size_t)blockIdx.x * blockDim.x + threadIdx.x;
    const size_t total = (size_t)MROWS * (DM / 2);
    if (idx >= total) return;
    const int pair = (int)(idx % (DM / 2));
    const size_t row = idx / (DM / 2);
    const int t = (int)(row % TT);
    const int i = pair % (HD / 2);
    const float inv_freq = powf(10000.0f, -2.0f * (float)i / (float)HD);
    const float ang = (float)t * inv_freq;
    const float c = cosf(ang), s = sinf(ang);
    const size_t base = row * DM + (size_t)pair * 2;
    float q1 = Q[base], q2 = Q[base + 1];
    Q[base]     = q1 * c - q2 * s;
    Q[base + 1] = q1 * s + q2 * c;
    float k1 = K[base], k2 = K[base + 1];
    K[base]     = k1 * c - k2 * s;
    K[base + 1] = k1 * s + k2 * c;
}

// ---------------------------------------------------------------------------
// Flash attention (unchanged from verified version).
// ---------------------------------------------------------------------------
#define FST 68

__global__ void __launch_bounds__(256) flash_attn(const float* __restrict__ Q,
                                                  const float* __restrict__ K,
                                                  const float* __restrict__ V,
                                                  float* __restrict__ O) {
    const int qt = blockIdx.x;
    const int h  = blockIdx.y;
    const int b  = blockIdx.z;
    const int tx = threadIdx.x, ty = threadIdx.y;
    const int tid = ty * 16 + tx;

    __shared__ float Qs[TQ][FST];
    __shared__ float KPs[TK][FST];   // K tile, reused as P tile
    __shared__ float Vs[TK][FST];

    const size_t base_bh = (size_t)(b * TT) * DM + h * HD;

    for (int u = tid; u < TQ * 16; u += 256) {
        const int r = u >> 4, d4 = u & 15;
        *(float4*)&Qs[r][d4 * 4] =
            *(const float4*)(Q + base_bh + (size_t)(qt * TQ + r) * DM + d4 * 4);
    }

    float o[4][4] = {};
    float mrow[4], lrow[4];
#pragma unroll
    for (int r = 0; r < 4; r++) { mrow[r] = -INFINITY; lrow[r] = 0.f; }

    for (int kt = 0; kt <= qt; kt++) {
        __syncthreads();
        for (int u = tid; u < TK * 16; u += 256) {
            const int r = u >> 4, d4 = u & 15;
            const size_t g = base_bh + (size_t)(kt * TK + r) * DM + d4 * 4;
            *(float4*)&KPs[r][d4 * 4] = *(const float4*)(K + g);
            *(float4*)&Vs[r][d4 * 4]  = *(const float4*)(V + g);
        }
        __syncthreads();

        float s[4][4] = {};
        for (int d4 = 0; d4 < HD / 4; d4++) {
            float a[4][4], kk[4][4];
#pragma unroll
            for (int r = 0; r < 4; r++) *(float4*)a[r] = *(const float4*)&Qs[ty * 4 + r][d4 * 4];
#pragma unroll
            for (int c = 0; c < 4; c++) *(float4*)kk[c] = *(const float4*)&KPs[tx * 4 + c][d4 * 4];
#pragma unroll
            for (int dd = 0; dd < 4; dd++)
#pragma unroll
                for (int r = 0; r < 4; r++)
#pragma unroll
                    for (int c = 0; c < 4; c++)
                        s[r][c] += a[r][dd] * kk[c][dd];
        }
#pragma unroll
        for (int r = 0; r < 4; r++)
#pragma unroll
            for (int c = 0; c < 4; c++)
                s[r][c] *= 0.125f;
        if (kt == qt) {
#pragma unroll
            for (int r = 0; r < 4; r++)
#pragma unroll
                for (int c = 0; c < 4; c++)
                    if (tx * 4 + c > ty * 4 + r) s[r][c] = -INFINITY;
        }

        float p[4][4];
#pragma unroll
        for (int r = 0; r < 4; r++) {
            float mx = fmaxf(fmaxf(s[r][0], s[r][1]), fmaxf(s[r][2], s[r][3]));
#pragma unroll
            for (int off = 8; off; off >>= 1) mx = fmaxf(mx, __shfl_xor(mx, off));
            const float mnew = fmaxf(mrow[r], mx);
            const float alpha = __expf(mrow[r] - mnew);
            float psum = 0.f;
#pragma unroll
            for (int c = 0; c < 4; c++) { p[r][c] = __expf(s[r][c] - mnew); psum += p[r][c]; }
#pragma unroll
            for (int off = 8; off; off >>= 1) psum += __shfl_xor(psum, off);
            mrow[r] = mnew;
            lrow[r] = lrow[r] * alpha + psum;
#pragma unroll
            for (int c = 0; c < 4; c++) o[r][c] *= alpha;
        }

        __syncthreads();
#pragma unroll
        for (int r = 0; r < 4; r++)
            *(float4*)&KPs[ty * 4 + r][tx * 4] = *(float4*)p[r];
        __syncthreads();

        for (int k4 = 0; k4 < TK / 4; k4++) {
            float pp[4][4], vv[4][4];
#pragma unroll
            for (int r = 0; r < 4; r++) *(float4*)pp[r] = *(const float4*)&KPs[ty * 4 + r][k4 * 4];
#pragma unroll
            for (int j = 0; j < 4; j++) *(float4*)vv[j] = *(const float4*)&Vs[k4 * 4 + j][tx * 4];
#pragma unroll
            for (int r = 0; r < 4; r++)
#pragma unroll
                for (int c = 0; c < 4; c++)
                    o[r][c] += pp[r][0] * vv[0][c] + pp[r][1] * vv[1][c]
                             + pp[r][2] * vv[2][c] + pp[r][3] * vv[3][c];
        }
    }

#pragma unroll
    for (int r = 0; r < 4; r++) {
        const float inv = 1.f / lrow[r];
        float4 res = make_float4(o[r][0] * inv, o[r][1] * inv, o[r][2] * inv, o[r][3] * inv);
        *(float4*)(O + base_bh + (size_t)(qt * TQ + ty * 4 + r) * DM + tx * 4) = res;
    }
}

// ---------------------------------------------------------------------------
extern "C" void kernel_launch(void* const* d_in, const int* in_sizes, int n_in,
                              void* d_out, int out_size, void* d_ws, size_t ws_size,
                              hipStream_t stream) {
    const void* x  = d_in[0];
    const void* wq = d_in[1];
    const void* wk = d_in[2];
    const void* wv = d_in[3];
    const void* wo = d_in[4];

    const size_t mat = (size_t)MROWS * DM;
    float* Q  = (float*)d_ws;
    float* Kp = Q  + mat;
    float* Vp = Kp + mat;
    float* Ao = Vp + mat;
    int* flag = (int*)((char*)d_ws + mat * 4 * sizeof(float));

    detect_dtype<<<1, 256, 0, stream>>>((const unsigned short*)x, flag);

    dim3 ggrid(DM / 128, MROWS / 128);   // 8 x 32 = 256 blocks
    gemm_mfma<0><<<ggrid, 256, 0, stream>>>(x, wq, Q, flag);
    gemm_mfma<0><<<ggrid, 256, 0, stream>>>(x, wk, Kp, flag);
    gemm_mfma<0><<<ggrid, 256, 0, stream>>>(x, wv, Vp, flag);

    const size_t rope_threads = (size_t)MROWS * (DM / 2);
    rope_kernel<<<(unsigned)((rope_threads + 255) / 256), 256, 0, stream>>>(Q, Kp);

    flash_attn<<<dim3(TT / TQ, NH, BB), dim3(16, 16), 0, stream>>>(Q, Kp, Vp, Ao);

    gemm_mfma<1><<<ggrid, 256, 0, stream>>>(Ao, wo, d_out, flag);
}

// Round 2
// 752.260 us; speedup vs baseline: 3.0084x; 1.4865x over previous
//
#include <hip/hip_runtime.h>
#include <hip/hip_bf16.h>
#include <math.h>

#define DM 1024
#define NH 16
#define HD 64
#define BB 2
#define TT 2048
#define MROWS (BB*TT)   // 4096

typedef __hip_bfloat16 bf16;
typedef unsigned short ushort_t;

using bf8_t = __attribute__((ext_vector_type(8))) __bf16;   // one MFMA A/B fragment (4 VGPRs)
using bf4_t = __attribute__((ext_vector_type(4))) __bf16;   // 8-byte LDS write chunk
using f4_t  = __attribute__((ext_vector_type(4))) float;    // MFMA C/D fragment

// ---------------------------------------------------------------------------
// Runtime input-dtype probe (flag=1 -> fp32 inputs, 0 -> bf16). Graph-safe.
// ---------------------------------------------------------------------------
__global__ void detect_dtype(const unsigned short* __restrict__ x, int* flag) {
    __shared__ int cnt;
    if (threadIdx.x == 0) cnt = 0;
    __syncthreads();
    int local = 0;
    for (int i = threadIdx.x; i < 512; i += 256) {
        unsigned short u = x[i];
        int e = (u >> 7) & 0xFF;
        if (e >= 117 && e <= 130) local++;
    }
    atomicAdd(&cnt, local);
    __syncthreads();
    if (threadIdx.x == 0) *flag = (cnt >= 384) ? 0 : 1;
}

// ---------------------------------------------------------------------------
// MFMA GEMM  Y[M,N] = A[M,K] * W[N,K]^T   (M=4096, N=K=1024)
// 128x128 tile, BK=64, 4 waves.  Error-free bf16 hi/lo splitting.
//   MODE 0: A dtype=flag, Y=f32 row-major.
//   MODE 1: A=f32 ws (always split), Y dtype=flag.
//   MODE 2: like MODE 0 but Y stored TRANSPOSED (f32, [N][MROWS]) -> for V.
// LDS XOR-swizzle byte ^= (row&7)<<4 (T2) for conflict-free ds_read_b128.
// ---------------------------------------------------------------------------
__device__ __forceinline__ int swz(int r, int b) {
    return r * 128 + (b ^ ((r & 7) << 4));
}

template<int MODE>
__global__ __launch_bounds__(256) void gemm_mfma(const void* __restrict__ A,
                                                 const void* __restrict__ W,
                                                 void* __restrict__ Y,
                                                 const int* __restrict__ flag)
{
    const int f32 = *flag;
    __shared__ __align__(16) char sm[65536];
    char* const Ah = sm;
    char* const Wh = sm + 16384;
    char* const Al = sm + 32768;
    char* const Wl = sm + 49152;

    const int tid  = threadIdx.x;
    const int m0   = blockIdx.y * 128, n0 = blockIdx.x * 128;
    const int lane = tid & 63;
    const int wr   = ((tid >> 7) & 1) * 64;
    const int wc   = ((tid >> 6) & 1) * 64;
    const int lrow = lane & 15;
    const int lkb  = (lane >> 4) * 16;

    const bool aSplit = (MODE == 1) || (f32 != 0);
    const bool wSplit = (f32 != 0);

    f4_t acc[4][4] = {};

    for (int k0 = 0; k0 < DM; k0 += 64) {
        if (k0) __syncthreads();

        if (!aSplit) {
            const ushort_t* Ab = (const ushort_t*)A;
            for (int u = tid; u < 1024; u += 256) {
                const int r = u >> 3, c = u & 7;
                bf8_t v = *(const bf8_t*)(Ab + (size_t)(m0 + r) * DM + k0 + c * 8);
                *(bf8_t*)(Ah + swz(r, c * 16)) = v;
            }
        } else {
            const float* Af = (const float*)A;
            for (int u = tid; u < 2048; u += 256) {
                const int r = u >> 4, c = u & 15;
                float4 v = *(const float4*)(Af + (size_t)(m0 + r) * DM + k0 + c * 4);
                __bf16 h0 = (__bf16)v.x, h1 = (__bf16)v.y,
                       h2 = (__bf16)v.z, h3 = (__bf16)v.w;
                bf4_t hv = {h0, h1, h2, h3};
                bf4_t lv = {(__bf16)(v.x - (float)h0), (__bf16)(v.y - (float)h1),
                            (__bf16)(v.z - (float)h2), (__bf16)(v.w - (float)h3)};
                *(bf4_t*)(Ah + swz(r, c * 8)) = hv;
                *(bf4_t*)(Al + swz(r, c * 8)) = lv;
            }
        }
        if (!wSplit) {
            const ushort_t* Wb = (const ushort_t*)W;
            for (int u = tid; u < 1024; u += 256) {
                const int r = u >> 3, c = u & 7;
                bf8_t v = *(const bf8_t*)(Wb + (size_t)(n0 + r) * DM + k0 + c * 8);
                *(bf8_t*)(Wh + swz(r, c * 16)) = v;
            }
        } else {
            const float* Wf = (const float*)W;
            for (int u = tid; u < 2048; u += 256) {
                const int r = u >> 4, c = u & 15;
                float4 v = *(const float4*)(Wf + (size_t)(n0 + r) * DM + k0 + c * 4);
                __bf16 h0 = (__bf16)v.x, h1 = (__bf16)v.y,
                       h2 = (__bf16)v.z, h3 = (__bf16)v.w;
                bf4_t hv = {h0, h1, h2, h3};
                bf4_t lv = {(__bf16)(v.x - (float)h0), (__bf16)(v.y - (float)h1),
                            (__bf16)(v.z - (float)h2), (__bf16)(v.w - (float)h3)};
                *(bf4_t*)(Wh + swz(r, c * 8)) = hv;
                *(bf4_t*)(Wl + swz(r, c * 8)) = lv;
            }
        }
        __syncthreads();

#pragma unroll
        for (int kh = 0; kh < 2; kh++) {
            const int bc = kh * 64 + lkb;
            bf8_t ah[4], wh[4], al[4], wl[4];
#pragma unroll
            for (int i = 0; i < 4; i++) {
                ah[i] = *(const bf8_t*)(Ah + swz(wr + i * 16 + lrow, bc));
                wh[i] = *(const bf8_t*)(Wh + swz(wc + i * 16 + lrow, bc));
            }
            if (aSplit) {
#pragma unroll
                for (int i = 0; i < 4; i++)
                    al[i] = *(const bf8_t*)(Al + swz(wr + i * 16 + lrow, bc));
            }
            if (wSplit) {
#pragma unroll
                for (int i = 0; i < 4; i++)
                    wl[i] = *(const bf8_t*)(Wl + swz(wc + i * 16 + lrow, bc));
            }
#pragma unroll
            for (int m = 0; m < 4; m++)
#pragma unroll
                for (int n = 0; n < 4; n++) {
                    acc[m][n] = __builtin_amdgcn_mfma_f32_16x16x32_bf16(
                                    ah[m], wh[n], acc[m][n], 0, 0, 0);
                    if (aSplit)
                        acc[m][n] = __builtin_amdgcn_mfma_f32_16x16x32_bf16(
                                        al[m], wh[n], acc[m][n], 0, 0, 0);
                    if (wSplit)
                        acc[m][n] = __builtin_amdgcn_mfma_f32_16x16x32_bf16(
                                        ah[m], wl[n], acc[m][n], 0, 0, 0);
                }
        }
    }

    const int orow = (lane >> 4) * 4;
    const int ocol = lane & 15;
#pragma unroll
    for (int m = 0; m < 4; m++)
#pragma unroll
        for (int n = 0; n < 4; n++) {
            const int gr = m0 + wr + m * 16 + orow;
            const int gc = n0 + wc + n * 16 + ocol;
            if (MODE == 2) {
                // transposed f32 store: Y[gc][gr..gr+3] (16B aligned, gr%4==0)
                *(f4_t*)((float*)Y + (size_t)gc * MROWS + gr) = acc[m][n];
            } else {
#pragma unroll
                for (int r = 0; r < 4; r++) {
                    const float v = acc[m][n][r];
                    const size_t off = (size_t)(gr + r) * DM + gc;
                    if (MODE == 0)      ((float*)Y)[off] = v;
                    else if (f32)       ((float*)Y)[off] = v;
                    else                ((__bf16*)Y)[off] = (__bf16)v;
                }
            }
        }
}

// ---------------------------------------------------------------------------
// RoPE in-place on Q and K, layout [B*T, DM].  (unchanged; V untouched)
// ---------------------------------------------------------------------------
__global__ void rope_kernel(float* __restrict__ Q, float* __restrict__ K) {
    const size_t idx = (size_t)blockIdx.x * blockDim.x + threadIdx.x;
    const size_t total = (size_t)MROWS * (DM / 2);
    if (idx >= total) return;
    const int pair = (int)(idx % (DM / 2));
    const size_t row = idx / (DM / 2);
    const int t = (int)(row % TT);
    const int i = pair % (HD / 2);
    const float inv_freq = powf(10000.0f, -2.0f * (float)i / (float)HD);
    const float ang = (float)t * inv_freq;
    const float c = cosf(ang), s = sinf(ang);
    const size_t base = row * DM + (size_t)pair * 2;
    float q1 = Q[base], q2 = Q[base + 1];
    Q[base]     = q1 * c - q2 * s;
    Q[base + 1] = q1 * s + q2 * c;
    float k1 = K[base], k2 = K[base + 1];
    K[base]     = k1 * c - k2 * s;
    K[base + 1] = k1 * s + k2 * c;
}

// ---------------------------------------------------------------------------
// MFMA flash attention.  Block = 256 thr (4 waves), q-tile 128 (32 rows/wave),
// k-tile 64.  K & V(transposed ws) staged hi/lo bf16 in swizzled LDS.
// QK^T: 3-term (qh*kh + ql*kh + qh*kl); PV: 3-term (ph*vh + pl*vh + ph*vl)
// -> fp32-class internals.  S and O share the C/D row layout so the online
// softmax rescale is per-lane scalar; P round-trips via swizzled f32 LDS
// (wave-private rows: no barrier, lgkmcnt(0)+sched_barrier only).
// LDS: Kh,Kl,Vh,Vl 4x8KB + P 32KB = 64KB -> 2 blocks/CU.
// ---------------------------------------------------------------------------
__device__ __forceinline__ int pswz(int row, int word) {
    return row * 256 + ((word * 4) ^ ((row & 7) << 4));
}

__global__ void __launch_bounds__(256) flash_attn_mfma(const float* __restrict__ Q,
                                                       const float* __restrict__ K,
                                                       const float* __restrict__ Vt,
                                                       float* __restrict__ O)
{
    __shared__ __align__(16) char sm[65536];
    char* const Kh = sm;
    char* const Kl = sm + 8192;
    char* const Vh = sm + 16384;
    char* const Vl = sm + 24576;
    char* const Pb = sm + 32768;   // [128][64] f32, pswz

    const int qt  = blockIdx.x;    // 0..15
    const int h   = blockIdx.y;
    const int b   = blockIdx.z;
    const int tid = threadIdx.x;
    const int lane = tid & 63;
    const int w    = tid >> 6;     // wave 0..3
    const int l15  = lane & 15;
    const int g    = lane >> 4;

    const size_t base_bh = (size_t)(b * TT) * DM + h * HD;
    const size_t base_v  = (size_t)(h * HD) * MROWS + (size_t)(b * TT);

    // ---- Q fragments (hi/lo), scale 1/sqrt(HD)=0.125 folded in (exact) ----
    bf8_t qh[2][2], ql[2][2];
#pragma unroll
    for (int m = 0; m < 2; m++)
#pragma unroll
        for (int kh = 0; kh < 2; kh++) {
            const float* qp = Q + base_bh +
                (size_t)(qt * 128 + w * 32 + m * 16 + l15) * DM + kh * 32 + g * 8;
            float4 a = *(const float4*)qp;
            float4 c = *(const float4*)(qp + 4);
            float f[8] = {a.x, a.y, a.z, a.w, c.x, c.y, c.z, c.w};
            bf8_t hh, ll;
#pragma unroll
            for (int j = 0; j < 8; j++) {
                float v = f[j] * 0.125f;
                __bf16 hb = (__bf16)v;
                hh[j] = hb;
                ll[j] = (__bf16)(v - (float)hb);
            }
            qh[m][kh] = hh; ql[m][kh] = ll;
        }

    f4_t o[2][4] = {};
    float mrow[2][4], lrow[2][4];
#pragma unroll
    for (int m = 0; m < 2; m++)
#pragma unroll
        for (int r = 0; r < 4; r++) { mrow[m][r] = -INFINITY; lrow[m][r] = 0.f; }

    const int nkt = 2 * qt + 2;
    for (int kt = 0; kt < nkt; kt++) {
        __syncthreads();   // previous tile's LDS readers done
        // ---- stage K (row-major) and V (transposed ws) hi/lo ----
        for (int u = tid; u < 1024; u += 256) {
            const int r = u >> 4, c = u & 15;
            {
                float4 v = *(const float4*)(K + base_bh + (size_t)(kt * 64 + r) * DM + c * 4);
                __bf16 h0 = (__bf16)v.x, h1 = (__bf16)v.y,
                       h2 = (__bf16)v.z, h3 = (__bf16)v.w;
                bf4_t hv = {h0, h1, h2, h3};
                bf4_t lv = {(__bf16)(v.x - (float)h0), (__bf16)(v.y - (float)h1),
                            (__bf16)(v.z - (float)h2), (__bf16)(v.w - (float)h3)};
                *(bf4_t*)(Kh + swz(r, c * 8)) = hv;
                *(bf4_t*)(Kl + swz(r, c * 8)) = lv;
            }
            {
                float4 v = *(const float4*)(Vt + base_v + (size_t)r * MROWS + kt * 64 + c * 4);
                __bf16 h0 = (__bf16)v.x, h1 = (__bf16)v.y,
                       h2 = (__bf16)v.z, h3 = (__bf16)v.w;
                bf4_t hv = {h0, h1, h2, h3};
                bf4_t lv = {(__bf16)(v.x - (float)h0), (__bf16)(v.y - (float)h1),
                            (__bf16)(v.z - (float)h2), (__bf16)(v.w - (float)h3)};
                *(bf4_t*)(Vh + swz(r, c * 8)) = hv;
                *(bf4_t*)(Vl + swz(r, c * 8)) = lv;
            }
        }
        __syncthreads();

        // ---- S = (Q/8) K^T : 3-term MFMA ----
        f4_t s[2][4] = {};
#pragma unroll
        for (int kh = 0; kh < 2; kh++)
#pragma unroll
            for (int n = 0; n < 4; n++) {
                bf8_t kf  = *(const bf8_t*)(Kh + swz(n * 16 + l15, kh * 64 + g * 16));
                bf8_t kl2 = *(const bf8_t*)(Kl + swz(n * 16 + l15, kh * 64 + g * 16));
#pragma unroll
                for (int m = 0; m < 2; m++) {
                    s[m][n] = __builtin_amdgcn_mfma_f32_16x16x32_bf16(qh[m][kh], kf,  s[m][n], 0, 0, 0);
                    s[m][n] = __builtin_amdgcn_mfma_f32_16x16x32_bf16(ql[m][kh], kf,  s[m][n], 0, 0, 0);
                    s[m][n] = __builtin_amdgcn_mfma_f32_16x16x32_bf16(qh[m][kh], kl2, s[m][n], 0, 0, 0);
                }
            }

        // ---- online softmax (rows: q = w*32 + m*16 + g*4 + r) ----
        const bool domask = (kt >= 2 * qt);
#pragma unroll
        for (int m = 0; m < 2; m++)
#pragma unroll
            for (int r = 0; r < 4; r++) {
                float s0 = s[m][0][r], s1 = s[m][1][r], s2 = s[m][2][r], s3 = s[m][3][r];
                if (domask) {
                    const int qg = qt * 128 + w * 32 + m * 16 + g * 4 + r;
                    const int kb = kt * 64 + l15;
                    if (kb      > qg) s0 = -INFINITY;
                    if (kb + 16 > qg) s1 = -INFINITY;
                    if (kb + 32 > qg) s2 = -INFINITY;
                    if (kb + 48 > qg) s3 = -INFINITY;
                }
                float mx = fmaxf(fmaxf(s0, s1), fmaxf(s2, s3));
                mx = fmaxf(mx, __shfl_xor(mx, 1));
                mx = fmaxf(mx, __shfl_xor(mx, 2));
                mx = fmaxf(mx, __shfl_xor(mx, 4));
                mx = fmaxf(mx, __shfl_xor(mx, 8));
                const float mold = mrow[m][r];
                const float mnew = fmaxf(mold, mx);
                const float alpha = __expf(mold - mnew);
                const float p0 = __expf(s0 - mnew);
                const float p1 = __expf(s1 - mnew);
                const float p2 = __expf(s2 - mnew);
                const float p3 = __expf(s3 - mnew);
                float ps = p0 + p1 + p2 + p3;
                ps += __shfl_xor(ps, 1);
                ps += __shfl_xor(ps, 2);
                ps += __shfl_xor(ps, 4);
                ps += __shfl_xor(ps, 8);
                mrow[m][r] = mnew;
                lrow[m][r] = lrow[m][r] * alpha + ps;
#pragma unroll
                for (int nf = 0; nf < 4; nf++) o[m][nf][r] *= alpha;
                const int qrow = w * 32 + m * 16 + g * 4 + r;
                *(float*)(Pb + pswz(qrow, 0 * 16 + l15)) = p0;
                *(float*)(Pb + pswz(qrow, 1 * 16 + l15)) = p1;
                *(float*)(Pb + pswz(qrow, 2 * 16 + l15)) = p2;
                *(float*)(Pb + pswz(qrow, 3 * 16 + l15)) = p3;
            }

        // wave-private P rows: wait own ds_writes, block scheduler motion
        asm volatile("s_waitcnt lgkmcnt(0)" ::: "memory");
        __builtin_amdgcn_sched_barrier(0);

        // ---- P fragments (hi/lo from f32 LDS) ----
        bf8_t ph[2][2], pl[2][2];
#pragma unroll
        for (int m = 0; m < 2; m++)
#pragma unroll
            for (int kh = 0; kh < 2; kh++) {
                const int qrow = w * 32 + m * 16 + l15;
                const int w0 = kh * 32 + g * 8;
                f4_t a  = *(const f4_t*)(Pb + pswz(qrow, w0));
                f4_t bb = *(const f4_t*)(Pb + pswz(qrow, w0 + 4));
                float f[8] = {a[0], a[1], a[2], a[3], bb[0], bb[1], bb[2], bb[3]};
                bf8_t hh, ll;
#pragma unroll
                for (int j = 0; j < 8; j++) {
                    __bf16 hb = (__bf16)f[j];
                    hh[j] = hb;
                    ll[j] = (__bf16)(f[j] - (float)hb);
                }
                ph[m][kh] = hh; pl[m][kh] = ll;
            }

        // ---- O += P V : 3-term MFMA ----
#pragma unroll
        for (int kh = 0; kh < 2; kh++)
#pragma unroll
            for (int nf = 0; nf < 4; nf++) {
                bf8_t vf  = *(const bf8_t*)(Vh + swz(nf * 16 + l15, kh * 64 + g * 16));
                bf8_t vl2 = *(const bf8_t*)(Vl + swz(nf * 16 + l15, kh * 64 + g * 16));
#pragma unroll
                for (int m = 0; m < 2; m++) {
                    o[m][nf] = __builtin_amdgcn_mfma_f32_16x16x32_bf16(ph[m][kh], vf,  o[m][nf], 0, 0, 0);
                    o[m][nf] = __builtin_amdgcn_mfma_f32_16x16x32_bf16(pl[m][kh], vf,  o[m][nf], 0, 0, 0);
                    o[m][nf] = __builtin_amdgcn_mfma_f32_16x16x32_bf16(ph[m][kh], vl2, o[m][nf], 0, 0, 0);
                }
            }
    }

    // ---- normalize + store ----
#pragma unroll
    for (int m = 0; m < 2; m++)
#pragma unroll
        for (int r = 0; r < 4; r++) {
            const float inv = 1.0f / lrow[m][r];
            const size_t row = (size_t)(qt * 128 + w * 32 + m * 16 + g * 4 + r);
#pragma unroll
            for (int nf = 0; nf < 4; nf++)
                O[base_bh + row * DM + nf * 16 + l15] = o[m][nf][r] * inv;
        }
}

// ---------------------------------------------------------------------------
extern "C" void kernel_launch(void* const* d_in, const int* in_sizes, int n_in,
                              void* d_out, int out_size, void* d_ws, size_t ws_size,
                              hipStream_t stream) {
    const void* x  = d_in[0];
    const void* wq = d_in[1];
    const void* wk = d_in[2];
    const void* wv = d_in[3];
    const void* wo = d_in[4];

    const size_t mat = (size_t)MROWS * DM;
    float* Q  = (float*)d_ws;
    float* Kp = Q  + mat;
    float* Vp = Kp + mat;      // transposed: [DM][MROWS]
    float* Ao = Vp + mat;
    int* flag = (int*)((char*)d_ws + mat * 4 * sizeof(float));

    detect_dtype<<<1, 256, 0, stream>>>((const unsigned short*)x, flag);

    dim3 ggrid(DM / 128, MROWS / 128);   // 8 x 32 = 256 blocks
    gemm_mfma<0><<<ggrid, 256, 0, stream>>>(x, wq, Q, flag);
    gemm_mfma<0><<<ggrid, 256, 0, stream>>>(x, wk, Kp, flag);
    gemm_mfma<2><<<ggrid, 256, 0, stream>>>(x, wv, Vp, flag);   // V transposed

    const size_t rope_threads = (size_t)MROWS * (DM / 2);
    rope_kernel<<<(unsigned)((rope_threads + 255) / 256), 256, 0, stream>>>(Q, Kp);

    flash_attn_mfma<<<dim3(TT / 128, NH, BB), 256, 0, stream>>>(Q, Kp, Vp, Ao);

    gemm_mfma<1><<<ggrid, 256, 0, stream>>>(Ao, wo, d_out, flag);
}